// Round 1
// baseline (11790.623 us; speedup 1.0000x reference)
//
#include <hip/hip_runtime.h>
#include <math.h>

#define SEQ    1024
#define DIM    1024
#define NH     16
#define HDIM   64
#define MLP    4096
#define NLAYER 4
#define BATCH  2
#define NTOK   (BATCH * SEQ)   // 2048 rows
#define LN_EPS 1e-5f

__device__ __forceinline__ float gelu_exact(float x) {
    return 0.5f * x * (1.0f + erff(x * 0.70710678118654752f));
}

// ---------------------------------------------------------------------------
// C[n][c] = act( sum_k A[n][k] * W[c][k] + bias[c] )
// A: [N,K] row-major, W: [Dout,K] row-major (torch linear layout, used as W^T)
// All dims multiples of 64/16 -> no edge guards needed.
// ---------------------------------------------------------------------------
__global__ __launch_bounds__(256)
void gemm_bias(const float* __restrict__ A, const float* __restrict__ W,
               const float* __restrict__ bias, float* __restrict__ C,
               int K, int Dout, int act)
{
    __shared__ float As[64][17];
    __shared__ float Ws[64][17];
    const int tid = threadIdx.x;
    const int tx = tid & 15, ty = tid >> 4;
    const int rowBase = blockIdx.y * 64;
    const int colBase = blockIdx.x * 64;
    const int lr = tid >> 2;          // 0..63 row within tile
    const int lk = (tid & 3) << 2;    // 0,4,8,12
    float acc[4][4] = {};
    const float* Arow = A + (size_t)(rowBase + lr) * K + lk;
    const float* Wrow = W + (size_t)(colBase + lr) * K + lk;
    for (int k0 = 0; k0 < K; k0 += 16) {
        float4 a4 = *reinterpret_cast<const float4*>(Arow + k0);
        float4 w4 = *reinterpret_cast<const float4*>(Wrow + k0);
        As[lr][lk + 0] = a4.x; As[lr][lk + 1] = a4.y;
        As[lr][lk + 2] = a4.z; As[lr][lk + 3] = a4.w;
        Ws[lr][lk + 0] = w4.x; Ws[lr][lk + 1] = w4.y;
        Ws[lr][lk + 2] = w4.z; Ws[lr][lk + 3] = w4.w;
        __syncthreads();
        #pragma unroll
        for (int kk = 0; kk < 16; ++kk) {
            float a[4], w[4];
            #pragma unroll
            for (int i = 0; i < 4; ++i) a[i] = As[ty * 4 + i][kk];
            #pragma unroll
            for (int j = 0; j < 4; ++j) w[j] = Ws[tx * 4 + j][kk];
            #pragma unroll
            for (int i = 0; i < 4; ++i)
                #pragma unroll
                for (int j = 0; j < 4; ++j)
                    acc[i][j] = fmaf(a[i], w[j], acc[i][j]);
        }
        __syncthreads();
    }
    #pragma unroll
    for (int i = 0; i < 4; ++i) {
        const int n = rowBase + ty * 4 + i;
        #pragma unroll
        for (int j = 0; j < 4; ++j) {
            const int c = colBase + tx * 4 + j;
            float v = acc[i][j] + bias[c];
            if (act) v = gelu_exact(v);
            C[(size_t)n * Dout + c] = v;
        }
    }
}

// ---------------------------------------------------------------------------
// Full attention, one block (256 thr) per (b,h,s) query row.
// qkv: [B*S, 3*DIM], q at col h*64, k at 1024+h*64, v at 2048+h*64.
// out: [B*S, DIM] heads re-merged.
// ---------------------------------------------------------------------------
__global__ __launch_bounds__(256)
void attn_full(const float* __restrict__ qkv, float* __restrict__ out)
{
    __shared__ float qs[HDIM];
    __shared__ float sc[SEQ];
    __shared__ float red[256];
    __shared__ float part[4][HDIM];
    const int gid = blockIdx.x;
    const int s = gid & (SEQ - 1);
    const int h = (gid >> 10) & (NH - 1);
    const int b = gid >> 14;
    const int tid = threadIdx.x;
    const size_t rowQ = (size_t)(b * SEQ + s) * (3 * DIM) + h * HDIM;
    if (tid < HDIM) qs[tid] = qkv[rowQ + tid];
    __syncthreads();

    // scores: each thread does 4 keys
    float lmax = -1e30f;
    #pragma unroll
    for (int c = 0; c < 4; ++c) {
        const int t = c * 256 + tid;
        const float4* kp4 = reinterpret_cast<const float4*>(
            &qkv[(size_t)(b * SEQ + t) * (3 * DIM) + DIM + h * HDIM]);
        float dot = 0.f;
        #pragma unroll
        for (int dd = 0; dd < 16; ++dd) {
            float4 k4 = kp4[dd];
            dot += qs[4 * dd + 0] * k4.x + qs[4 * dd + 1] * k4.y
                 + qs[4 * dd + 2] * k4.z + qs[4 * dd + 3] * k4.w;
        }
        dot *= 0.125f;              // 1/sqrt(64)
        sc[t] = dot;
        lmax = fmaxf(lmax, dot);
    }
    red[tid] = lmax;
    __syncthreads();
    for (int ofs = 128; ofs > 0; ofs >>= 1) {
        if (tid < ofs) red[tid] = fmaxf(red[tid], red[tid + ofs]);
        __syncthreads();
    }
    const float m = red[0];
    __syncthreads();

    float lsum = 0.f;
    #pragma unroll
    for (int c = 0; c < 4; ++c) {
        const int t = c * 256 + tid;
        const float e = __expf(sc[t] - m);
        sc[t] = e;
        lsum += e;
    }
    red[tid] = lsum;
    __syncthreads();
    for (int ofs = 128; ofs > 0; ofs >>= 1) {
        if (tid < ofs) red[tid] += red[tid + ofs];
        __syncthreads();
    }
    const float denom = red[0];
    __syncthreads();

    // PV: thread (d = tid&63, chunk c = tid>>6) accumulates 256 keys
    const int d = tid & 63, c = tid >> 6;
    float acc = 0.f;
    for (int i = 0; i < 256; ++i) {
        const int t = c * 256 + i;
        acc += sc[t] * qkv[(size_t)(b * SEQ + t) * (3 * DIM) + 2 * DIM + h * HDIM + d];
    }
    part[c][d] = acc;
    __syncthreads();
    if (tid < HDIM) {
        const float o = (part[0][tid] + part[1][tid] + part[2][tid] + part[3][tid]) / denom;
        out[(size_t)(b * SEQ + s) * DIM + h * HDIM + tid] = o;
    }
}

// ---------------------------------------------------------------------------
// Banded attention (|s-t| <= 2), one wave per (b,h,s). lane = head dim.
// ---------------------------------------------------------------------------
__global__ __launch_bounds__(64)
void attn_band(const float* __restrict__ qkv, float* __restrict__ out)
{
    const int gid = blockIdx.x;
    const int s = gid & (SEQ - 1);
    const int h = (gid >> 10) & (NH - 1);
    const int b = gid >> 14;
    const int lane = threadIdx.x;
    const float qd = qkv[(size_t)(b * SEQ + s) * (3 * DIM) + h * HDIM + lane];
    const int t0 = max(s - 2, 0);
    const int t1 = min(s + 2, SEQ - 1);
    const int cnt = t1 - t0 + 1;
    float p[5];
    float m = -1e30f;
    for (int i = 0; i < cnt; ++i) {
        const int t = t0 + i;
        float prod = qd * qkv[(size_t)(b * SEQ + t) * (3 * DIM) + DIM + h * HDIM + lane];
        #pragma unroll
        for (int off = 32; off > 0; off >>= 1) prod += __shfl_xor(prod, off);
        p[i] = prod * 0.125f;
        m = fmaxf(m, p[i]);
    }
    float sum = 0.f;
    for (int i = 0; i < cnt; ++i) { p[i] = __expf(p[i] - m); sum += p[i]; }
    float acc = 0.f;
    for (int i = 0; i < cnt; ++i)
        acc += p[i] * qkv[(size_t)(b * SEQ + t0 + i) * (3 * DIM) + 2 * DIM + h * HDIM + lane];
    out[(size_t)(b * SEQ + s) * DIM + h * HDIM + lane] = acc / sum;
}

// ---------------------------------------------------------------------------
// out[n][:] = LN( x[n][:] (+ y[n][:]) ) * g + b   — one block per row
// ---------------------------------------------------------------------------
__global__ __launch_bounds__(256)
void add_ln(const float* __restrict__ x, const float* __restrict__ y,
            const float* __restrict__ g, const float* __restrict__ be,
            float* __restrict__ out, int hasY)
{
    __shared__ float row[DIM];
    __shared__ float red[256];
    const int n = blockIdx.x;
    const int tid = threadIdx.x;
    float lsum = 0.f;
    for (int i = tid; i < DIM; i += 256) {
        float v = x[(size_t)n * DIM + i];
        if (hasY) v += y[(size_t)n * DIM + i];
        row[i] = v;
        lsum += v;
    }
    red[tid] = lsum;
    __syncthreads();
    for (int ofs = 128; ofs > 0; ofs >>= 1) {
        if (tid < ofs) red[tid] += red[tid + ofs];
        __syncthreads();
    }
    const float mu = red[0] * (1.f / DIM);
    __syncthreads();
    float lvar = 0.f;
    for (int i = tid; i < DIM; i += 256) {
        const float d = row[i] - mu;
        lvar += d * d;
    }
    red[tid] = lvar;
    __syncthreads();
    for (int ofs = 128; ofs > 0; ofs >>= 1) {
        if (tid < ofs) red[tid] += red[tid + ofs];
        __syncthreads();
    }
    const float rstd = rsqrtf(red[0] * (1.f / DIM) + LN_EPS);
    __syncthreads();
    for (int i = tid; i < DIM; i += 256)
        out[(size_t)n * DIM + i] = (row[i] - mu) * rstd * g[i] + be[i];
}

__global__ __launch_bounds__(256)
void add_vec(const float* __restrict__ a, const float* __restrict__ b,
             float* __restrict__ out)
{
    const size_t i = (size_t)blockIdx.x * 256 + threadIdx.x;
    out[i] = a[i] + b[i];
}

// ---------------------------------------------------------------------------
extern "C" void kernel_launch(void* const* d_in, const int* in_sizes, int n_in,
                              void* d_out, int out_size, void* d_ws, size_t ws_size,
                              hipStream_t stream)
{
    const float* x0     = (const float*)d_in[0];
    const float* w_in1  = (const float*)d_in[1];
    const float* b_in1  = (const float*)d_in[2];
    const float* w_out1 = (const float*)d_in[3];
    const float* b_out1 = (const float*)d_in[4];
    const float* ln1_g  = (const float*)d_in[5];
    const float* ln1_b  = (const float*)d_in[6];
    const float* w_in2  = (const float*)d_in[7];
    const float* b_in2  = (const float*)d_in[8];
    const float* w_out2 = (const float*)d_in[9];
    const float* b_out2 = (const float*)d_in[10];
    const float* ln2_g  = (const float*)d_in[11];
    const float* ln2_b  = (const float*)d_in[12];
    const float* fw1    = (const float*)d_in[13];
    const float* fb1    = (const float*)d_in[14];
    const float* fw2    = (const float*)d_in[15];
    const float* fb2    = (const float*)d_in[16];
    const float* lnf_g  = (const float*)d_in[17];
    const float* lnf_b  = (const float*)d_in[18];
    float* out = (float*)d_out;

    float* ws   = (float*)d_ws;
    float* xb   = ws;                                  // 2M floats
    float* qkvb = ws + (size_t)2 * 1024 * 1024;        // 8M floats (qkv / ffn hidden)
    float* t1   = ws + (size_t)10 * 1024 * 1024;       // 2M floats (attn out / attended)
    float* t2   = ws + (size_t)12 * 1024 * 1024;       // 2M floats (proj / ffn2 out)
    float* att  = t1;                                  // alias: t1 free when att is live

    hipMemcpyAsync(xb, x0, sizeof(float) * (size_t)NTOK * DIM,
                   hipMemcpyDeviceToDevice, stream);

    const dim3 blk(256);
    for (int l = 0; l < NLAYER; ++l) {
        const float* wi1 = w_in1  + (size_t)l * 3 * DIM * DIM;
        const float* bi1 = b_in1  + (size_t)l * 3 * DIM;
        const float* wo1 = w_out1 + (size_t)l * DIM * DIM;
        const float* bo1 = b_out1 + (size_t)l * DIM;
        const float* g1  = ln1_g  + (size_t)l * DIM;
        const float* be1 = ln1_b  + (size_t)l * DIM;
        const float* wi2 = w_in2  + (size_t)l * 3 * DIM * DIM;
        const float* bi2 = b_in2  + (size_t)l * 3 * DIM;
        const float* wo2 = w_out2 + (size_t)l * DIM * DIM;
        const float* bo2 = b_out2 + (size_t)l * DIM;
        const float* g2  = ln2_g  + (size_t)l * DIM;
        const float* be2 = ln2_b  + (size_t)l * DIM;
        const float* w1l = fw1    + (size_t)l * MLP * DIM;
        const float* b1l = fb1    + (size_t)l * MLP;
        const float* w2l = fw2    + (size_t)l * DIM * MLP;
        const float* b2l = fb2    + (size_t)l * DIM;

        // 1. qkv1 = x @ w_in1^T + b_in1
        gemm_bias<<<dim3(3 * DIM / 64, NTOK / 64), blk, 0, stream>>>(
            xb, wi1, bi1, qkvb, DIM, 3 * DIM, 0);
        // 2. full attention
        attn_full<<<dim3(BATCH * NH * SEQ), blk, 0, stream>>>(qkvb, t1);
        // 3. proj
        gemm_bias<<<dim3(DIM / 64, NTOK / 64), blk, 0, stream>>>(
            t1, wo1, bo1, t2, DIM, DIM, 0);
        // 4. x = LN(x + proj)
        add_ln<<<dim3(NTOK), blk, 0, stream>>>(xb, t2, g1, be1, xb, 1);
        // 5. qkv2
        gemm_bias<<<dim3(3 * DIM / 64, NTOK / 64), blk, 0, stream>>>(
            xb, wi2, bi2, qkvb, DIM, 3 * DIM, 0);
        // 6. banded attention
        attn_band<<<dim3(BATCH * NH * SEQ), dim3(64), 0, stream>>>(qkvb, t1);
        // 7. proj2
        gemm_bias<<<dim3(DIM / 64, NTOK / 64), blk, 0, stream>>>(
            t1, wo2, bo2, t2, DIM, DIM, 0);
        // 8. attended = LN(x + proj2)   (att aliases t1; t1 consumed in step 7)
        add_ln<<<dim3(NTOK), blk, 0, stream>>>(xb, t2, g2, be2, att, 1);
        // 9. h = gelu(att @ fw1^T + fb1)
        gemm_bias<<<dim3(MLP / 64, NTOK / 64), blk, 0, stream>>>(
            att, w1l, b1l, qkvb, DIM, MLP, 1);
        // 10. t2 = h @ fw2^T + fb2
        gemm_bias<<<dim3(DIM / 64, NTOK / 64), blk, 0, stream>>>(
            qkvb, w2l, b2l, t2, MLP, DIM, 0);
        // 11. x = attended + t2
        add_vec<<<dim3(NTOK * DIM / 256), blk, 0, stream>>>(att, t2, xb);
    }
    // final LN
    add_ln<<<dim3(NTOK), blk, 0, stream>>>(xb, nullptr, lnf_g, lnf_b, out, 0);
}

// Round 2
// 2787.781 us; speedup vs baseline: 4.2294x; 4.2294x over previous
//
#include <hip/hip_runtime.h>
#include <math.h>

#define SEQ    1024
#define DIM    1024
#define NH     16
#define HDIM   64
#define MLP    4096
#define NLAYER 4
#define BATCH  2
#define NTOK   (BATCH * SEQ)   // 2048 rows
#define LN_EPS 1e-5f

typedef __attribute__((ext_vector_type(8))) short bf16x8;
typedef __attribute__((ext_vector_type(4))) float f32x4;

__device__ __forceinline__ float gelu_exact(float x) {
    return 0.5f * x * (1.0f + erff(x * 0.70710678118654752f));
}

__device__ __forceinline__ unsigned int pack2bf(float a, float b) {
    union { float f; unsigned int u; } va, vb;
    va.f = a; vb.f = b;
    unsigned int ua = va.u + 0x7fffu + ((va.u >> 16) & 1u);
    unsigned int ub = vb.u + 0x7fffu + ((vb.u >> 16) & 1u);
    return (ua >> 16) | (ub & 0xffff0000u);
}

// ---------------------------------------------------------------------------
// C[n][c] = act( sum_k A[n][k] * W[c][k] + bias[c] )  via bf16 MFMA
// A: [M,K] fp32 row-major; W: [Dout,K] fp32 row-major (torch linear layout).
// BM=128, BK=32. Block = 256 thr = 4 waves (2x2), wave = 64 x (BN/2) output.
// ---------------------------------------------------------------------------
template<int BN>
__global__ __launch_bounds__(256)
void gemm_mfma(const float* __restrict__ A, const float* __restrict__ W,
               const float* __restrict__ bias, float* __restrict__ C,
               int K, int Dout, int act)
{
    constexpr int NT = BN / 32;             // MFMA n-tiles per wave
    __shared__ unsigned short As[128][40];  // 32 + 8 pad (80B rows, 16B-aligned)
    __shared__ unsigned short Ws[BN][40];
    const int t = threadIdx.x;
    const int wave = t >> 6, lane = t & 63;
    const int quad = lane >> 4, l16 = lane & 15;
    const int wm = (wave >> 1) * 64;
    const int wn = (wave & 1) * (BN / 2);
    const int rowBase = blockIdx.y * 128;
    const int colBase = blockIdx.x * BN;

    f32x4 acc[4][NT];
    #pragma unroll
    for (int mt = 0; mt < 4; ++mt)
        #pragma unroll
        for (int nt = 0; nt < NT; ++nt)
            acc[mt][nt] = (f32x4){0.f, 0.f, 0.f, 0.f};

    for (int k0 = 0; k0 < K; k0 += 32) {
        __syncthreads();
        // stage A: 128x32 fp32 -> bf16 LDS. 512 chunks of 8 floats.
        #pragma unroll
        for (int i = 0; i < 2; ++i) {
            const int c = t + 256 * i;
            const int row = c >> 2, c0 = (c & 3) * 8;
            const float* src = A + (size_t)(rowBase + row) * K + k0 + c0;
            float4 f0 = *(const float4*)(src);
            float4 f1 = *(const float4*)(src + 4);
            uint4 pk = { pack2bf(f0.x, f0.y), pack2bf(f0.z, f0.w),
                         pack2bf(f1.x, f1.y), pack2bf(f1.z, f1.w) };
            *(uint4*)&As[row][c0] = pk;
        }
        // stage W: BNx32
        #pragma unroll
        for (int i = 0; i < BN / 64; ++i) {
            const int c = t + 256 * i;
            const int row = c >> 2, c0 = (c & 3) * 8;
            const float* src = W + (size_t)(colBase + row) * K + k0 + c0;
            float4 f0 = *(const float4*)(src);
            float4 f1 = *(const float4*)(src + 4);
            uint4 pk = { pack2bf(f0.x, f0.y), pack2bf(f0.z, f0.w),
                         pack2bf(f1.x, f1.y), pack2bf(f1.z, f1.w) };
            *(uint4*)&Ws[row][c0] = pk;
        }
        __syncthreads();
        bf16x8 af[4], bfr[NT];
        #pragma unroll
        for (int mt = 0; mt < 4; ++mt)
            af[mt] = *(const bf16x8*)&As[wm + mt * 16 + l16][quad * 8];
        #pragma unroll
        for (int nt = 0; nt < NT; ++nt)
            bfr[nt] = *(const bf16x8*)&Ws[wn + nt * 16 + l16][quad * 8];
        #pragma unroll
        for (int mt = 0; mt < 4; ++mt)
            #pragma unroll
            for (int nt = 0; nt < NT; ++nt)
                acc[mt][nt] = __builtin_amdgcn_mfma_f32_16x16x32_bf16(
                    af[mt], bfr[nt], acc[mt][nt], 0, 0, 0);
    }
    // epilogue: D layout row = quad*4 + reg, col = lane&15
    #pragma unroll
    for (int mt = 0; mt < 4; ++mt) {
        #pragma unroll
        for (int nt = 0; nt < NT; ++nt) {
            const int col = colBase + wn + nt * 16 + l16;
            const float bv = bias[col];
            #pragma unroll
            for (int r = 0; r < 4; ++r) {
                const int row = rowBase + wm + mt * 16 + quad * 4 + r;
                float v = acc[mt][nt][r] + bv;
                if (act) v = gelu_exact(v);
                C[(size_t)row * Dout + col] = v;
            }
        }
    }
}

// ---------------------------------------------------------------------------
// Tiled flash-style full attention (fp32). One block = 32 queries of one (b,h).
// Thread t: query q = t>>3, dim-chunk d0 = (t&7)*8, keys j = (t&7) + 8*jj.
// ---------------------------------------------------------------------------
__global__ __launch_bounds__(256)
void attn_full(const float* __restrict__ qkv, float* __restrict__ out)
{
    __shared__ float Qs[32][68];
    __shared__ float Ks[64][68];
    __shared__ float Vs[64][68];
    __shared__ float Ps[32][68];
    __shared__ float redm[32][8];
    __shared__ float reds[32][8];
    __shared__ float mrow[32], lrow[32], alph[32];

    const int blk = blockIdx.x;
    const int q0 = (blk & 31) * 32;
    const int h = (blk >> 5) & 15;
    const int b = blk >> 9;
    const int t = threadIdx.x;
    const int q = t >> 3, g = t & 7, d0 = g * 8;

    {
        const float* src = qkv + (size_t)(b * SEQ + q0 + q) * (3 * DIM) + h * HDIM + d0;
        *(float4*)&Qs[q][d0]     = *(const float4*)src;
        *(float4*)&Qs[q][d0 + 4] = *(const float4*)(src + 4);
    }
    if (t < 32) { mrow[t] = -1e30f; lrow[t] = 0.f; }
    float O[8] = {0.f, 0.f, 0.f, 0.f, 0.f, 0.f, 0.f, 0.f};

    for (int kt = 0; kt < SEQ / 64; ++kt) {
        __syncthreads();   // prev tile fully consumed; Q/init visible on iter 0
        #pragma unroll
        for (int i = 0; i < 2; ++i) {
            const int c = t + 256 * i;
            const int row = c >> 3, c0 = (c & 7) * 8;
            const float* src = qkv + (size_t)(b * SEQ + kt * 64 + row) * (3 * DIM)
                             + h * HDIM + c0;
            *(float4*)&Ks[row][c0]     = *(const float4*)(src + DIM);
            *(float4*)&Ks[row][c0 + 4] = *(const float4*)(src + DIM + 4);
            *(float4*)&Vs[row][c0]     = *(const float4*)(src + 2 * DIM);
            *(float4*)&Vs[row][c0 + 4] = *(const float4*)(src + 2 * DIM + 4);
        }
        __syncthreads();
        // scores for keys j = g + 8*jj
        float sc[8] = {0.f, 0.f, 0.f, 0.f, 0.f, 0.f, 0.f, 0.f};
        for (int kk = 0; kk < 64; kk += 4) {
            float4 q4 = *(float4*)&Qs[q][kk];
            #pragma unroll
            for (int jj = 0; jj < 8; ++jj) {
                float4 k4 = *(float4*)&Ks[8 * jj + g][kk];
                sc[jj] += q4.x * k4.x + q4.y * k4.y + q4.z * k4.z + q4.w * k4.w;
            }
        }
        float pm = -1e30f;
        #pragma unroll
        for (int jj = 0; jj < 8; ++jj) { sc[jj] *= 0.125f; pm = fmaxf(pm, sc[jj]); }
        redm[q][g] = pm;
        __syncthreads();
        if (t < 32) {
            float tm = redm[t][0];
            #pragma unroll
            for (int j = 1; j < 8; ++j) tm = fmaxf(tm, redm[t][j]);
            const float mo = mrow[t], mn = fmaxf(mo, tm);
            alph[t] = __expf(mo - mn);
            mrow[t] = mn;
        }
        __syncthreads();
        const float m = mrow[q];
        float ps = 0.f;
        #pragma unroll
        for (int jj = 0; jj < 8; ++jj) {
            const float p = __expf(sc[jj] - m);
            ps += p;
            Ps[q][8 * jj + g] = p;
        }
        reds[q][g] = ps;
        const float al = alph[q];
        #pragma unroll
        for (int d = 0; d < 8; ++d) O[d] *= al;
        __syncthreads();
        if (t < 32) {
            float s = 0.f;
            #pragma unroll
            for (int j = 0; j < 8; ++j) s += reds[t][j];
            lrow[t] = lrow[t] * alph[t] + s;
        }
        // PV accumulate (overlaps leader's lrow update; Ps/Vs ready)
        #pragma unroll
        for (int j4 = 0; j4 < 16; ++j4) {
            float4 p4 = *(float4*)&Ps[q][j4 * 4];
            #pragma unroll
            for (int e = 0; e < 4; ++e) {
                const float pe = (e == 0) ? p4.x : (e == 1) ? p4.y : (e == 2) ? p4.z : p4.w;
                const int j = j4 * 4 + e;
                float4 v0 = *(float4*)&Vs[j][d0];
                float4 v1 = *(float4*)&Vs[j][d0 + 4];
                O[0] += pe * v0.x; O[1] += pe * v0.y; O[2] += pe * v0.z; O[3] += pe * v0.w;
                O[4] += pe * v1.x; O[5] += pe * v1.y; O[6] += pe * v1.z; O[7] += pe * v1.w;
            }
        }
    }
    __syncthreads();
    const float inv = 1.f / lrow[q];
    float4 o0 = {O[0] * inv, O[1] * inv, O[2] * inv, O[3] * inv};
    float4 o1 = {O[4] * inv, O[5] * inv, O[6] * inv, O[7] * inv};
    float* dst = out + (size_t)(b * SEQ + q0 + q) * DIM + h * HDIM + d0;
    *(float4*)dst = o0;
    *(float4*)(dst + 4) = o1;
}

// ---------------------------------------------------------------------------
// Banded attention (|s-t| <= 2), one wave per (b,h,s). lane = head dim.
// ---------------------------------------------------------------------------
__global__ __launch_bounds__(64)
void attn_band(const float* __restrict__ qkv, float* __restrict__ out)
{
    const int gid = blockIdx.x;
    const int s = gid & (SEQ - 1);
    const int h = (gid >> 10) & (NH - 1);
    const int b = gid >> 14;
    const int lane = threadIdx.x;
    const float qd = qkv[(size_t)(b * SEQ + s) * (3 * DIM) + h * HDIM + lane];
    const int t0 = max(s - 2, 0);
    const int t1 = min(s + 2, SEQ - 1);
    const int cnt = t1 - t0 + 1;
    float p[5];
    float m = -1e30f;
    for (int i = 0; i < cnt; ++i) {
        const int tt = t0 + i;
        float prod = qd * qkv[(size_t)(b * SEQ + tt) * (3 * DIM) + DIM + h * HDIM + lane];
        #pragma unroll
        for (int off = 32; off > 0; off >>= 1) prod += __shfl_xor(prod, off);
        p[i] = prod * 0.125f;
        m = fmaxf(m, p[i]);
    }
    float sum = 0.f;
    for (int i = 0; i < cnt; ++i) { p[i] = __expf(p[i] - m); sum += p[i]; }
    float acc = 0.f;
    for (int i = 0; i < cnt; ++i)
        acc += p[i] * qkv[(size_t)(b * SEQ + t0 + i) * (3 * DIM) + 2 * DIM + h * HDIM + lane];
    out[(size_t)(b * SEQ + s) * DIM + h * HDIM + lane] = acc / sum;
}

// ---------------------------------------------------------------------------
// out[n][:] = LN( x[n][:] (+ y[n][:]) ) * g + b   — one block per row
// ---------------------------------------------------------------------------
__global__ __launch_bounds__(256)
void add_ln(const float* __restrict__ x, const float* __restrict__ y,
            const float* __restrict__ g, const float* __restrict__ be,
            float* __restrict__ out, int hasY)
{
    __shared__ float row[DIM];
    __shared__ float red[256];
    const int n = blockIdx.x;
    const int tid = threadIdx.x;
    float lsum = 0.f;
    for (int i = tid; i < DIM; i += 256) {
        float v = x[(size_t)n * DIM + i];
        if (hasY) v += y[(size_t)n * DIM + i];
        row[i] = v;
        lsum += v;
    }
    red[tid] = lsum;
    __syncthreads();
    for (int ofs = 128; ofs > 0; ofs >>= 1) {
        if (tid < ofs) red[tid] += red[tid + ofs];
        __syncthreads();
    }
    const float mu = red[0] * (1.f / DIM);
    __syncthreads();
    float lvar = 0.f;
    for (int i = tid; i < DIM; i += 256) {
        const float d = row[i] - mu;
        lvar += d * d;
    }
    red[tid] = lvar;
    __syncthreads();
    for (int ofs = 128; ofs > 0; ofs >>= 1) {
        if (tid < ofs) red[tid] += red[tid + ofs];
        __syncthreads();
    }
    const float rstd = rsqrtf(red[0] * (1.f / DIM) + LN_EPS);
    __syncthreads();
    for (int i = tid; i < DIM; i += 256)
        out[(size_t)n * DIM + i] = (row[i] - mu) * rstd * g[i] + be[i];
}

__global__ __launch_bounds__(256)
void add_vec(const float* __restrict__ a, const float* __restrict__ b,
             float* __restrict__ out)
{
    const size_t i = (size_t)blockIdx.x * 256 + threadIdx.x;
    out[i] = a[i] + b[i];
}

// ---------------------------------------------------------------------------
extern "C" void kernel_launch(void* const* d_in, const int* in_sizes, int n_in,
                              void* d_out, int out_size, void* d_ws, size_t ws_size,
                              hipStream_t stream)
{
    const float* x0     = (const float*)d_in[0];
    const float* w_in1  = (const float*)d_in[1];
    const float* b_in1  = (const float*)d_in[2];
    const float* w_out1 = (const float*)d_in[3];
    const float* b_out1 = (const float*)d_in[4];
    const float* ln1_g  = (const float*)d_in[5];
    const float* ln1_b  = (const float*)d_in[6];
    const float* w_in2  = (const float*)d_in[7];
    const float* b_in2  = (const float*)d_in[8];
    const float* w_out2 = (const float*)d_in[9];
    const float* b_out2 = (const float*)d_in[10];
    const float* ln2_g  = (const float*)d_in[11];
    const float* ln2_b  = (const float*)d_in[12];
    const float* fw1    = (const float*)d_in[13];
    const float* fb1    = (const float*)d_in[14];
    const float* fw2    = (const float*)d_in[15];
    const float* fb2    = (const float*)d_in[16];
    const float* lnf_g  = (const float*)d_in[17];
    const float* lnf_b  = (const float*)d_in[18];
    float* out = (float*)d_out;

    float* ws   = (float*)d_ws;
    float* xb   = ws;                                  // 2M floats
    float* qkvb = ws + (size_t)2 * 1024 * 1024;        // 8M floats (qkv / ffn hidden)
    float* t1   = ws + (size_t)10 * 1024 * 1024;       // 2M floats (attn out / attended)
    float* t2   = ws + (size_t)12 * 1024 * 1024;       // 2M floats (proj / ffn2 out)
    float* att  = t1;                                  // alias: t1 free when att is live

    hipMemcpyAsync(xb, x0, sizeof(float) * (size_t)NTOK * DIM,
                   hipMemcpyDeviceToDevice, stream);

    const dim3 blk(256);
    for (int l = 0; l < NLAYER; ++l) {
        const float* wi1 = w_in1  + (size_t)l * 3 * DIM * DIM;
        const float* bi1 = b_in1  + (size_t)l * 3 * DIM;
        const float* wo1 = w_out1 + (size_t)l * DIM * DIM;
        const float* bo1 = b_out1 + (size_t)l * DIM;
        const float* g1  = ln1_g  + (size_t)l * DIM;
        const float* be1 = ln1_b  + (size_t)l * DIM;
        const float* wi2 = w_in2  + (size_t)l * 3 * DIM * DIM;
        const float* bi2 = b_in2  + (size_t)l * 3 * DIM;
        const float* wo2 = w_out2 + (size_t)l * DIM * DIM;
        const float* bo2 = b_out2 + (size_t)l * DIM;
        const float* g2  = ln2_g  + (size_t)l * DIM;
        const float* be2 = ln2_b  + (size_t)l * DIM;
        const float* w1l = fw1    + (size_t)l * MLP * DIM;
        const float* b1l = fb1    + (size_t)l * MLP;
        const float* w2l = fw2    + (size_t)l * DIM * MLP;
        const float* b2l = fb2    + (size_t)l * DIM;

        // 1. qkv1 = x @ w_in1^T + b_in1
        gemm_mfma<128><<<dim3(3 * DIM / 128, NTOK / 128), blk, 0, stream>>>(
            xb, wi1, bi1, qkvb, DIM, 3 * DIM, 0);
        // 2. full attention
        attn_full<<<dim3(BATCH * NH * (SEQ / 32)), blk, 0, stream>>>(qkvb, t1);
        // 3. proj
        gemm_mfma<64><<<dim3(DIM / 64, NTOK / 128), blk, 0, stream>>>(
            t1, wo1, bo1, t2, DIM, DIM, 0);
        // 4. x = LN(x + proj)
        add_ln<<<dim3(NTOK), blk, 0, stream>>>(xb, t2, g1, be1, xb, 1);
        // 5. qkv2
        gemm_mfma<128><<<dim3(3 * DIM / 128, NTOK / 128), blk, 0, stream>>>(
            xb, wi2, bi2, qkvb, DIM, 3 * DIM, 0);
        // 6. banded attention
        attn_band<<<dim3(BATCH * NH * SEQ), dim3(64), 0, stream>>>(qkvb, t1);
        // 7. proj2
        gemm_mfma<64><<<dim3(DIM / 64, NTOK / 128), blk, 0, stream>>>(
            t1, wo2, bo2, t2, DIM, DIM, 0);
        // 8. attended = LN(x + proj2)
        add_ln<<<dim3(NTOK), blk, 0, stream>>>(xb, t2, g2, be2, att, 1);
        // 9. h = gelu(att @ fw1^T + fb1)
        gemm_mfma<128><<<dim3(MLP / 128, NTOK / 128), blk, 0, stream>>>(
            att, w1l, b1l, qkvb, DIM, MLP, 1);
        // 10. t2 = h @ fw2^T + fb2
        gemm_mfma<64><<<dim3(DIM / 64, NTOK / 128), blk, 0, stream>>>(
            qkvb, w2l, b2l, t2, MLP, DIM, 0);
        // 11. x = attended + t2
        add_vec<<<dim3(NTOK * DIM / 256), blk, 0, stream>>>(att, t2, xb);
    }
    // final LN
    add_ln<<<dim3(NTOK), blk, 0, stream>>>(xb, nullptr, lnf_g, lnf_b, out, 0);
}

// Round 4
// 2090.697 us; speedup vs baseline: 5.6396x; 1.3334x over previous
//
#include <hip/hip_runtime.h>
#include <math.h>

#define SEQ    1024
#define DIM    1024
#define NH     16
#define HDIM   64
#define MLP    4096
#define NLAYER 4
#define BATCH  2
#define NTOK   (BATCH * SEQ)   // 2048 rows
#define LN_EPS 1e-5f

typedef __attribute__((ext_vector_type(8))) short bf16x8;
typedef __attribute__((ext_vector_type(4))) float f32x4;

__device__ __forceinline__ float gelu_exact(float x) {
    return 0.5f * x * (1.0f + erff(x * 0.70710678118654752f));
}

// software RNE fp32->bf16 pack: low16 = bf16(a), high16 = bf16(b)  [verified R2]
__device__ __forceinline__ unsigned int pack2bf(float a, float b) {
    union { float f; unsigned int u; } va, vb;
    va.f = a; vb.f = b;
    unsigned int ua = va.u + 0x7fffu + ((va.u >> 16) & 1u);
    unsigned int ub = vb.u + 0x7fffu + ((vb.u >> 16) & 1u);
    return (ua >> 16) | (ub & 0xffff0000u);
}
__device__ __forceinline__ unsigned short bf16lo(float a) {
    return (unsigned short)(pack2bf(a, 0.f) & 0xffffu);
}

// ---------------------------------------------------------------------------
// C[n][c] = act( sum_k A[n][k] * W[c][k] + bias[c] )  via bf16 MFMA
// A: [M,K] fp32 row-major; W: [Dout,K] fp32 row-major (torch linear layout).
// BM=128, BK=32. Block = 256 thr = 4 waves (2x2), wave = 64 x (BN/2) output.
// ---------------------------------------------------------------------------
template<int BN>
__global__ __launch_bounds__(256)
void gemm_mfma(const float* __restrict__ A, const float* __restrict__ W,
               const float* __restrict__ bias, float* __restrict__ C,
               int K, int Dout, int act)
{
    constexpr int NT = BN / 32;             // MFMA n-tiles per wave
    __shared__ unsigned short As[128][40];  // 32 + 8 pad (80B rows, 16B-aligned)
    __shared__ unsigned short Ws[BN][40];
    const int t = threadIdx.x;
    const int wave = t >> 6, lane = t & 63;
    const int quad = lane >> 4, l16 = lane & 15;
    const int wm = (wave >> 1) * 64;
    const int wn = (wave & 1) * (BN / 2);
    const int rowBase = blockIdx.y * 128;
    const int colBase = blockIdx.x * BN;

    f32x4 acc[4][NT];
    #pragma unroll
    for (int mt = 0; mt < 4; ++mt)
        #pragma unroll
        for (int nt = 0; nt < NT; ++nt)
            acc[mt][nt] = (f32x4){0.f, 0.f, 0.f, 0.f};

    for (int k0 = 0; k0 < K; k0 += 32) {
        __syncthreads();
        // stage A: 128x32 fp32 -> bf16 LDS. 512 chunks of 8 floats.
        #pragma unroll
        for (int i = 0; i < 2; ++i) {
            const int c = t + 256 * i;
            const int row = c >> 2, c0 = (c & 3) * 8;
            const float* src = A + (size_t)(rowBase + row) * K + k0 + c0;
            float4 f0 = *(const float4*)(src);
            float4 f1 = *(const float4*)(src + 4);
            uint4 pk = { pack2bf(f0.x, f0.y), pack2bf(f0.z, f0.w),
                         pack2bf(f1.x, f1.y), pack2bf(f1.z, f1.w) };
            *(uint4*)&As[row][c0] = pk;
        }
        // stage W: BNx32
        #pragma unroll
        for (int i = 0; i < BN / 64; ++i) {
            const int c = t + 256 * i;
            const int row = c >> 2, c0 = (c & 3) * 8;
            const float* src = W + (size_t)(colBase + row) * K + k0 + c0;
            float4 f0 = *(const float4*)(src);
            float4 f1 = *(const float4*)(src + 4);
            uint4 pk = { pack2bf(f0.x, f0.y), pack2bf(f0.z, f0.w),
                         pack2bf(f1.x, f1.y), pack2bf(f1.z, f1.w) };
            *(uint4*)&Ws[row][c0] = pk;
        }
        __syncthreads();
        bf16x8 af[4], bfr[NT];
        #pragma unroll
        for (int mt = 0; mt < 4; ++mt)
            af[mt] = *(const bf16x8*)&As[wm + mt * 16 + l16][quad * 8];
        #pragma unroll
        for (int nt = 0; nt < NT; ++nt)
            bfr[nt] = *(const bf16x8*)&Ws[wn + nt * 16 + l16][quad * 8];
        #pragma unroll
        for (int mt = 0; mt < 4; ++mt)
            #pragma unroll
            for (int nt = 0; nt < NT; ++nt)
                acc[mt][nt] = __builtin_amdgcn_mfma_f32_16x16x32_bf16(
                    af[mt], bfr[nt], acc[mt][nt], 0, 0, 0);
    }
    // epilogue: D layout row = quad*4 + reg, col = lane&15
    #pragma unroll
    for (int mt = 0; mt < 4; ++mt) {
        #pragma unroll
        for (int nt = 0; nt < NT; ++nt) {
            const int col = colBase + wn + nt * 16 + l16;
            const float bv = bias[col];
            #pragma unroll
            for (int r = 0; r < 4; ++r) {
                const int row = rowBase + wm + mt * 16 + quad * 4 + r;
                float v = acc[mt][nt][r] + bv;
                if (act) v = gelu_exact(v);
                C[(size_t)row * Dout + col] = v;
            }
        }
    }
}

// ---------------------------------------------------------------------------
// MFMA flash attention. Block = 256 thr = 4 waves; 64 queries (16/wave) of
// one (b,h). K-tiles of 64 keys staged bf16 in LDS (V transposed).
// QK^T and PV via mfma_f32_16x16x32_bf16, online softmax in registers.
// ---------------------------------------------------------------------------
__global__ __launch_bounds__(256)
void attn_full(const float* __restrict__ qkv, float* __restrict__ out)
{
    __shared__ unsigned short Qs[64][72];
    __shared__ unsigned short Ks[64][72];
    __shared__ unsigned short VT[64][72];        // VT[d][key]
    __shared__ unsigned short Ps[4][16][72];     // per-wave P buffer

    const int blk = blockIdx.x;
    const int q0 = (blk & 15) * 64;
    const int h  = (blk >> 4) & 15;
    const int b  = blk >> 8;
    const int t  = threadIdx.x;
    const int w = t >> 6, lane = t & 63;
    const int quad = lane >> 4, l16 = lane & 15;
    const int srow = t >> 2, sc0 = (t & 3) * 16;   // staging: row 0..63, col {0,16,32,48}

    // ---- stage Q (64x64 fp32 -> bf16) ----
    {
        const float* src = qkv + (size_t)(b * SEQ + q0 + srow) * (3 * DIM) + h * HDIM + sc0;
        float4 f0 = *(const float4*)(src);
        float4 f1 = *(const float4*)(src + 4);
        float4 f2 = *(const float4*)(src + 8);
        float4 f3 = *(const float4*)(src + 12);
        uint4 p0 = { pack2bf(f0.x, f0.y), pack2bf(f0.z, f0.w),
                     pack2bf(f1.x, f1.y), pack2bf(f1.z, f1.w) };
        uint4 p1 = { pack2bf(f2.x, f2.y), pack2bf(f2.z, f2.w),
                     pack2bf(f3.x, f3.y), pack2bf(f3.z, f3.w) };
        *(uint4*)&Qs[srow][sc0]     = p0;
        *(uint4*)&Qs[srow][sc0 + 8] = p1;
    }
    __syncthreads();

    // Q fragments for this wave (rows w*16 + l16), fixed across K loop
    bf16x8 aq[2];
    aq[0] = *(const bf16x8*)&Qs[w * 16 + l16][quad * 8];
    aq[1] = *(const bf16x8*)&Qs[w * 16 + l16][32 + quad * 8];

    float m_r[4] = {-1e30f, -1e30f, -1e30f, -1e30f};
    float l_r[4] = {0.f, 0.f, 0.f, 0.f};
    f32x4 Oa[4];
    #pragma unroll
    for (int nt = 0; nt < 4; ++nt) Oa[nt] = (f32x4){0.f, 0.f, 0.f, 0.f};

    for (int kt = 0; kt < SEQ / 64; ++kt) {
        __syncthreads();   // previous tile fully consumed
        // ---- stage K tile + V tile (transposed) ----
        {
            const float* srcK = qkv + (size_t)(b * SEQ + kt * 64 + srow) * (3 * DIM)
                              + DIM + h * HDIM + sc0;
            float4 f0 = *(const float4*)(srcK);
            float4 f1 = *(const float4*)(srcK + 4);
            float4 f2 = *(const float4*)(srcK + 8);
            float4 f3 = *(const float4*)(srcK + 12);
            uint4 p0 = { pack2bf(f0.x, f0.y), pack2bf(f0.z, f0.w),
                         pack2bf(f1.x, f1.y), pack2bf(f1.z, f1.w) };
            uint4 p1 = { pack2bf(f2.x, f2.y), pack2bf(f2.z, f2.w),
                         pack2bf(f3.x, f3.y), pack2bf(f3.z, f3.w) };
            *(uint4*)&Ks[srow][sc0]     = p0;
            *(uint4*)&Ks[srow][sc0 + 8] = p1;

            const float* srcV = srcK + DIM;
            f0 = *(const float4*)(srcV);
            f1 = *(const float4*)(srcV + 4);
            f2 = *(const float4*)(srcV + 8);
            f3 = *(const float4*)(srcV + 12);
            unsigned int pv[8] = {
                pack2bf(f0.x, f0.y), pack2bf(f0.z, f0.w),
                pack2bf(f1.x, f1.y), pack2bf(f1.z, f1.w),
                pack2bf(f2.x, f2.y), pack2bf(f2.z, f2.w),
                pack2bf(f3.x, f3.y), pack2bf(f3.z, f3.w) };
            #pragma unroll
            for (int i = 0; i < 8; ++i) {
                VT[sc0 + 2 * i][srow]     = (unsigned short)(pv[i] & 0xffffu);
                VT[sc0 + 2 * i + 1][srow] = (unsigned short)(pv[i] >> 16);
            }
        }
        __syncthreads();

        // ---- QK^T: S[16q x 64keys] ----
        f32x4 s[4];
        #pragma unroll
        for (int nt = 0; nt < 4; ++nt) {
            bf16x8 bk0 = *(const bf16x8*)&Ks[nt * 16 + l16][quad * 8];
            bf16x8 bk1 = *(const bf16x8*)&Ks[nt * 16 + l16][32 + quad * 8];
            s[nt] = __builtin_amdgcn_mfma_f32_16x16x32_bf16(aq[0], bk0,
                        (f32x4){0.f, 0.f, 0.f, 0.f}, 0, 0, 0);
            s[nt] = __builtin_amdgcn_mfma_f32_16x16x32_bf16(aq[1], bk1, s[nt], 0, 0, 0);
        }
        // scale + row max (row = quad*4+r, cols spread over nt regs and l16 lanes)
        float tm[4], alpha[4];
        #pragma unroll
        for (int r = 0; r < 4; ++r) {
            float v = fmaxf(fmaxf(s[0][r], s[1][r]), fmaxf(s[2][r], s[3][r])) * 0.125f;
            #pragma unroll
            for (int off = 1; off < 16; off <<= 1) v = fmaxf(v, __shfl_xor(v, off));
            tm[r] = v;
        }
        #pragma unroll
        for (int r = 0; r < 4; ++r) {
            const float mn = fmaxf(m_r[r], tm[r]);
            alpha[r] = __expf(m_r[r] - mn);
            m_r[r] = mn;
        }
        // exp + row sum + write P (bf16) to this wave's LDS buffer
        float rs[4] = {0.f, 0.f, 0.f, 0.f};
        #pragma unroll
        for (int nt = 0; nt < 4; ++nt) {
            #pragma unroll
            for (int r = 0; r < 4; ++r) {
                const float p = __expf(s[nt][r] * 0.125f - m_r[r]);
                rs[r] += p;
                Ps[w][quad * 4 + r][nt * 16 + l16] = bf16lo(p);
            }
        }
        #pragma unroll
        for (int r = 0; r < 4; ++r) {
            float v = rs[r];
            #pragma unroll
            for (int off = 1; off < 16; off <<= 1) v += __shfl_xor(v, off);
            l_r[r] = l_r[r] * alpha[r] + v;
            #pragma unroll
            for (int nt = 0; nt < 4; ++nt) Oa[nt][r] *= alpha[r];
        }
        // ---- PV: O += P[16x64] @ V[64x64] ----
        bf16x8 pa0 = *(const bf16x8*)&Ps[w][l16][quad * 8];
        bf16x8 pa1 = *(const bf16x8*)&Ps[w][l16][32 + quad * 8];
        #pragma unroll
        for (int nt = 0; nt < 4; ++nt) {
            bf16x8 bv0 = *(const bf16x8*)&VT[nt * 16 + l16][quad * 8];
            bf16x8 bv1 = *(const bf16x8*)&VT[nt * 16 + l16][32 + quad * 8];
            Oa[nt] = __builtin_amdgcn_mfma_f32_16x16x32_bf16(pa0, bv0, Oa[nt], 0, 0, 0);
            Oa[nt] = __builtin_amdgcn_mfma_f32_16x16x32_bf16(pa1, bv1, Oa[nt], 0, 0, 0);
        }
    }

    // ---- epilogue ----
    float inv[4];
    #pragma unroll
    for (int r = 0; r < 4; ++r) inv[r] = 1.f / l_r[r];
    #pragma unroll
    for (int r = 0; r < 4; ++r) {
        const int row = b * SEQ + q0 + w * 16 + quad * 4 + r;
        float* dst = out + (size_t)row * DIM + h * HDIM + l16;
        #pragma unroll
        for (int nt = 0; nt < 4; ++nt)
            dst[nt * 16] = Oa[nt][r] * inv[r];
    }
}

// ---------------------------------------------------------------------------
// Banded attention (|s-t| <= 2), one wave per (b,h,s). lane = head dim.
// ---------------------------------------------------------------------------
__global__ __launch_bounds__(64)
void attn_band(const float* __restrict__ qkv, float* __restrict__ out)
{
    const int gid = blockIdx.x;
    const int s = gid & (SEQ - 1);
    const int h = (gid >> 10) & (NH - 1);
    const int b = gid >> 14;
    const int lane = threadIdx.x;
    const float qd = qkv[(size_t)(b * SEQ + s) * (3 * DIM) + h * HDIM + lane];
    const int t0 = max(s - 2, 0);
    const int t1 = min(s + 2, SEQ - 1);
    const int cnt = t1 - t0 + 1;
    float p[5];
    float m = -1e30f;
    for (int i = 0; i < cnt; ++i) {
        const int tt = t0 + i;
        float prod = qd * qkv[(size_t)(b * SEQ + tt) * (3 * DIM) + DIM + h * HDIM + lane];
        #pragma unroll
        for (int off = 32; off > 0; off >>= 1) prod += __shfl_xor(prod, off);
        p[i] = prod * 0.125f;
        m = fmaxf(m, p[i]);
    }
    float sum = 0.f;
    for (int i = 0; i < cnt; ++i) { p[i] = __expf(p[i] - m); sum += p[i]; }
    float acc = 0.f;
    for (int i = 0; i < cnt; ++i)
        acc += p[i] * qkv[(size_t)(b * SEQ + t0 + i) * (3 * DIM) + 2 * DIM + h * HDIM + lane];
    out[(size_t)(b * SEQ + s) * DIM + h * HDIM + lane] = acc / sum;
}

// ---------------------------------------------------------------------------
// out[n][:] = LN( x[n][:] (+ y[n][:]) ) * g + b   — one block per row
// ---------------------------------------------------------------------------
__global__ __launch_bounds__(256)
void add_ln(const float* __restrict__ x, const float* __restrict__ y,
            const float* __restrict__ g, const float* __restrict__ be,
            float* __restrict__ out, int hasY)
{
    __shared__ float row[DIM];
    __shared__ float red[256];
    const int n = blockIdx.x;
    const int tid = threadIdx.x;
    float lsum = 0.f;
    for (int i = tid; i < DIM; i += 256) {
        float v = x[(size_t)n * DIM + i];
        if (hasY) v += y[(size_t)n * DIM + i];
        row[i] = v;
        lsum += v;
    }
    red[tid] = lsum;
    __syncthreads();
    for (int ofs = 128; ofs > 0; ofs >>= 1) {
        if (tid < ofs) red[tid] += red[tid + ofs];
        __syncthreads();
    }
    const float mu = red[0] * (1.f / DIM);
    __syncthreads();
    float lvar = 0.f;
    for (int i = tid; i < DIM; i += 256) {
        const float d = row[i] - mu;
        lvar += d * d;
    }
    red[tid] = lvar;
    __syncthreads();
    for (int ofs = 128; ofs > 0; ofs >>= 1) {
        if (tid < ofs) red[tid] += red[tid + ofs];
        __syncthreads();
    }
    const float rstd = rsqrtf(red[0] * (1.f / DIM) + LN_EPS);
    __syncthreads();
    for (int i = tid; i < DIM; i += 256)
        out[(size_t)n * DIM + i] = (row[i] - mu) * rstd * g[i] + be[i];
}

__global__ __launch_bounds__(256)
void add_vec(const float* __restrict__ a, const float* __restrict__ b,
             float* __restrict__ out)
{
    const size_t i = (size_t)blockIdx.x * 256 + threadIdx.x;
    out[i] = a[i] + b[i];
}

// ---------------------------------------------------------------------------
extern "C" void kernel_launch(void* const* d_in, const int* in_sizes, int n_in,
                              void* d_out, int out_size, void* d_ws, size_t ws_size,
                              hipStream_t stream)
{
    const float* x0     = (const float*)d_in[0];
    const float* w_in1  = (const float*)d_in[1];
    const float* b_in1  = (const float*)d_in[2];
    const float* w_out1 = (const float*)d_in[3];
    const float* b_out1 = (const float*)d_in[4];
    const float* ln1_g  = (const float*)d_in[5];
    const float* ln1_b  = (const float*)d_in[6];
    const float* w_in2  = (const float*)d_in[7];
    const float* b_in2  = (const float*)d_in[8];
    const float* w_out2 = (const float*)d_in[9];
    const float* b_out2 = (const float*)d_in[10];
    const float* ln2_g  = (const float*)d_in[11];
    const float* ln2_b  = (const float*)d_in[12];
    const float* fw1    = (const float*)d_in[13];
    const float* fb1    = (const float*)d_in[14];
    const float* fw2    = (const float*)d_in[15];
    const float* fb2    = (const float*)d_in[16];
    const float* lnf_g  = (const float*)d_in[17];
    const float* lnf_b  = (const float*)d_in[18];
    float* out = (float*)d_out;

    float* ws   = (float*)d_ws;
    float* xb   = ws;                                  // 2M floats
    float* qkvb = ws + (size_t)2 * 1024 * 1024;        // 8M floats (qkv / ffn hidden)
    float* t1   = ws + (size_t)10 * 1024 * 1024;       // 2M floats (attn out / attended)
    float* t2   = ws + (size_t)12 * 1024 * 1024;       // 2M floats (proj / ffn2 out)
    float* att  = t1;                                  // alias: t1 free when att is live

    hipMemcpyAsync(xb, x0, sizeof(float) * (size_t)NTOK * DIM,
                   hipMemcpyDeviceToDevice, stream);

    const dim3 blk(256);
    for (int l = 0; l < NLAYER; ++l) {
        const float* wi1 = w_in1  + (size_t)l * 3 * DIM * DIM;
        const float* bi1 = b_in1  + (size_t)l * 3 * DIM;
        const float* wo1 = w_out1 + (size_t)l * DIM * DIM;
        const float* bo1 = b_out1 + (size_t)l * DIM;
        const float* g1  = ln1_g  + (size_t)l * DIM;
        const float* be1 = ln1_b  + (size_t)l * DIM;
        const float* wi2 = w_in2  + (size_t)l * 3 * DIM * DIM;
        const float* bi2 = b_in2  + (size_t)l * 3 * DIM;
        const float* wo2 = w_out2 + (size_t)l * DIM * DIM;
        const float* bo2 = b_out2 + (size_t)l * DIM;
        const float* g2  = ln2_g  + (size_t)l * DIM;
        const float* be2 = ln2_b  + (size_t)l * DIM;
        const float* w1l = fw1    + (size_t)l * MLP * DIM;
        const float* b1l = fb1    + (size_t)l * MLP;
        const float* w2l = fw2    + (size_t)l * DIM * MLP;
        const float* b2l = fb2    + (size_t)l * DIM;

        // 1. qkv1 = x @ w_in1^T + b_in1
        gemm_mfma<128><<<dim3(3 * DIM / 128, NTOK / 128), blk, 0, stream>>>(
            xb, wi1, bi1, qkvb, DIM, 3 * DIM, 0);
        // 2. full attention (MFMA flash)
        attn_full<<<dim3(BATCH * NH * (SEQ / 64)), blk, 0, stream>>>(qkvb, t1);
        // 3. proj
        gemm_mfma<64><<<dim3(DIM / 64, NTOK / 128), blk, 0, stream>>>(
            t1, wo1, bo1, t2, DIM, DIM, 0);
        // 4. x = LN(x + proj)
        add_ln<<<dim3(NTOK), blk, 0, stream>>>(xb, t2, g1, be1, xb, 1);
        // 5. qkv2
        gemm_mfma<128><<<dim3(3 * DIM / 128, NTOK / 128), blk, 0, stream>>>(
            xb, wi2, bi2, qkvb, DIM, 3 * DIM, 0);
        // 6. banded attention
        attn_band<<<dim3(BATCH * NH * SEQ), dim3(64), 0, stream>>>(qkvb, t1);
        // 7. proj2
        gemm_mfma<64><<<dim3(DIM / 64, NTOK / 128), blk, 0, stream>>>(
            t1, wo2, bo2, t2, DIM, DIM, 0);
        // 8. attended = LN(x + proj2)
        add_ln<<<dim3(NTOK), blk, 0, stream>>>(xb, t2, g2, be2, att, 1);
        // 9. h = gelu(att @ fw1^T + fb1)
        gemm_mfma<128><<<dim3(MLP / 128, NTOK / 128), blk, 0, stream>>>(
            att, w1l, b1l, qkvb, DIM, MLP, 1);
        // 10. t2 = h @ fw2^T + fb2
        gemm_mfma<64><<<dim3(DIM / 64, NTOK / 128), blk, 0, stream>>>(
            qkvb, w2l, b2l, t2, MLP, DIM, 0);
        // 11. x = attended + t2
        add_vec<<<dim3(NTOK * DIM / 256), blk, 0, stream>>>(att, t2, xb);
    }
    // final LN
    add_ln<<<dim3(NTOK), blk, 0, stream>>>(xb, nullptr, lnf_g, lnf_b, out, 0);
}

// Round 5
// 1340.459 us; speedup vs baseline: 8.7960x; 1.5597x over previous
//
#include <hip/hip_runtime.h>
#include <math.h>

#define SEQ    1024
#define DIM    1024
#define NH     16
#define HDIM   64
#define MLP    4096
#define NLAYER 4
#define BATCH  2
#define NTOK   (BATCH * SEQ)
#define LN_EPS 1e-5f

typedef unsigned short ushortx;
typedef __attribute__((ext_vector_type(8))) short bf16x8;
typedef __attribute__((ext_vector_type(8))) unsigned short u16x8;
typedef __attribute__((ext_vector_type(4))) float f32x4;

__device__ __forceinline__ float gelu_exact(float x) {
    return 0.5f * x * (1.0f + erff(x * 0.70710678118654752f));
}
// software RNE fp32->bf16 pack (verified R2/R4)
__device__ __forceinline__ unsigned int pack2bf(float a, float b) {
    union { float f; unsigned int u; } va, vb;
    va.f = a; vb.f = b;
    unsigned int ua = va.u + 0x7fffu + ((va.u >> 16) & 1u);
    unsigned int ub = vb.u + 0x7fffu + ((vb.u >> 16) & 1u);
    return (ua >> 16) | (ub & 0xffff0000u);
}
__device__ __forceinline__ ushortx bf16lo(float a) {
    return (ushortx)(pack2bf(a, 0.f) & 0xffffu);
}
__device__ __forceinline__ float bf2f(ushortx u) {
    union { unsigned int i; float f; } v; v.i = ((unsigned int)u) << 16; return v.f;
}

// ---------------------------------------------------------------------------
// Per-layer weight fp32 -> bf16 conversion into contiguous ws region.
// Segment layout (elems): wi1@0(3M) wo1@3M(1M) wi2@4M(3M) wo2@7M(1M)
//                         w1@8M(4M) w2@12M(4M). Total 16M elems.
// ---------------------------------------------------------------------------
__global__ __launch_bounds__(256)
void cvt_w(const float* __restrict__ s0, const float* __restrict__ s1,
           const float* __restrict__ s2, const float* __restrict__ s3,
           const float* __restrict__ s4, const float* __restrict__ s5,
           ushortx* __restrict__ dst)
{
    const size_t total = 4194304;  // in float4 units
    for (size_t g = (size_t)blockIdx.x * 256 + threadIdx.x; g < total;
         g += (size_t)gridDim.x * 256) {
        const float* src; size_t base;
        if      (g <  786432) { src = s0; base = 0; }
        else if (g < 1048576) { src = s1; base =  786432; }
        else if (g < 1835008) { src = s2; base = 1048576; }
        else if (g < 2097152) { src = s3; base = 1835008; }
        else if (g < 3145728) { src = s4; base = 2097152; }
        else                  { src = s5; base = 3145728; }
        float4 f = *(const float4*)(src + (g - base) * 4);
        ushort4 o = { bf16lo(f.x), bf16lo(f.y), bf16lo(f.z), bf16lo(f.w) };
        *(ushort4*)(dst + g * 4) = o;
    }
}

__global__ __launch_bounds__(256)
void init_x(const float* __restrict__ x0, float* __restrict__ xb,
            ushortx* __restrict__ xbf)
{
    const size_t i = (size_t)blockIdx.x * 256 + threadIdx.x;
    const float v = x0[i];
    xb[i] = v;
    xbf[i] = bf16lo(v);
}

// ---------------------------------------------------------------------------
// bf16 GEMM, register-prefetch pipelined. A:[M,K] bf16, W:[N,K] bf16,
// bias fp32. BK=64. Block=256=4 waves (2x2), wave tile (BM/2)x(BN/2).
// MODE 0: fp32 out [M,N]. MODE 1: gelu + bf16 out [M,N].
// MODE 2: qkv out — cols<2048 -> bf16 qk[tok][2048]; cols>=2048 -> vT
//         [(b*16+h)*64+d][SEQ] bf16 (packed 4-token 8B stores).
// ---------------------------------------------------------------------------
template<int BM, int BN, int MODE>
__global__ __launch_bounds__(256)
void gemm_bf(const ushortx* __restrict__ A, const ushortx* __restrict__ W,
             const float* __restrict__ bias, void* __restrict__ Cout,
             void* __restrict__ Vout, int K, int N)
{
    constexpr int MT = BM / 32, NT = BN / 32;
    constexpr int AI = BM / 32, WI = BN / 32;   // 16B chunks per thread
    __shared__ ushortx As[BM][72];
    __shared__ ushortx Ws[BN][72];
    const int t = threadIdx.x;
    const int wave = t >> 6, lane = t & 63, quad = lane >> 4, l16 = lane & 15;
    const int wm = (wave >> 1) * (BM / 2);
    const int wn = (wave & 1) * (BN / 2);
    const int rowBase = blockIdx.y * BM, colBase = blockIdx.x * BN;

    f32x4 acc[MT][NT];
    #pragma unroll
    for (int mt = 0; mt < MT; ++mt)
        #pragma unroll
        for (int nt = 0; nt < NT; ++nt) acc[mt][nt] = (f32x4){0.f, 0.f, 0.f, 0.f};

    u16x8 aR[AI], wR[WI];
    #pragma unroll
    for (int i = 0; i < AI; ++i) {
        const int c = t + 256 * i, r = c >> 3, c8 = (c & 7) * 8;
        aR[i] = *(const u16x8*)(A + (size_t)(rowBase + r) * K + c8);
    }
    #pragma unroll
    for (int i = 0; i < WI; ++i) {
        const int c = t + 256 * i, r = c >> 3, c8 = (c & 7) * 8;
        wR[i] = *(const u16x8*)(W + (size_t)(colBase + r) * K + c8);
    }
    const int nIt = K / 64;
    for (int kt = 0; kt < nIt; ++kt) {
        __syncthreads();
        #pragma unroll
        for (int i = 0; i < AI; ++i) {
            const int c = t + 256 * i;
            *(u16x8*)&As[c >> 3][(c & 7) * 8] = aR[i];
        }
        #pragma unroll
        for (int i = 0; i < WI; ++i) {
            const int c = t + 256 * i;
            *(u16x8*)&Ws[c >> 3][(c & 7) * 8] = wR[i];
        }
        __syncthreads();
        if (kt + 1 < nIt) {   // prefetch next tile; overlaps MFMA below
            const int k0 = (kt + 1) * 64;
            #pragma unroll
            for (int i = 0; i < AI; ++i) {
                const int c = t + 256 * i, r = c >> 3, c8 = (c & 7) * 8;
                aR[i] = *(const u16x8*)(A + (size_t)(rowBase + r) * K + k0 + c8);
            }
            #pragma unroll
            for (int i = 0; i < WI; ++i) {
                const int c = t + 256 * i, r = c >> 3, c8 = (c & 7) * 8;
                wR[i] = *(const u16x8*)(W + (size_t)(colBase + r) * K + k0 + c8);
            }
        }
        #pragma unroll
        for (int kk = 0; kk < 2; ++kk) {
            bf16x8 af[MT], bfv[NT];
            #pragma unroll
            for (int mt = 0; mt < MT; ++mt)
                af[mt] = *(const bf16x8*)&As[wm + mt * 16 + l16][kk * 32 + quad * 8];
            #pragma unroll
            for (int nt = 0; nt < NT; ++nt)
                bfv[nt] = *(const bf16x8*)&Ws[wn + nt * 16 + l16][kk * 32 + quad * 8];
            #pragma unroll
            for (int mt = 0; mt < MT; ++mt)
                #pragma unroll
                for (int nt = 0; nt < NT; ++nt)
                    acc[mt][nt] = __builtin_amdgcn_mfma_f32_16x16x32_bf16(
                        af[mt], bfv[nt], acc[mt][nt], 0, 0, 0);
        }
    }
    // epilogue: D layout row = quad*4 + r, col = l16
    #pragma unroll
    for (int mt = 0; mt < MT; ++mt) {
        #pragma unroll
        for (int nt = 0; nt < NT; ++nt) {
            const int colTile = colBase + wn + nt * 16;
            const int col = colTile + l16;
            const float bv = bias[col];
            const int rbase = rowBase + wm + mt * 16 + quad * 4;
            if (MODE == 0) {
                float* C = (float*)Cout;
                #pragma unroll
                for (int r = 0; r < 4; ++r)
                    C[(size_t)(rbase + r) * N + col] = acc[mt][nt][r] + bv;
            } else if (MODE == 1) {
                ushortx* C = (ushortx*)Cout;
                #pragma unroll
                for (int r = 0; r < 4; ++r)
                    C[(size_t)(rbase + r) * N + col] = bf16lo(gelu_exact(acc[mt][nt][r] + bv));
            } else {
                if (colTile < 2 * DIM) {
                    ushortx* C = (ushortx*)Cout;
                    #pragma unroll
                    for (int r = 0; r < 4; ++r)
                        C[(size_t)(rbase + r) * (2 * DIM) + col] = bf16lo(acc[mt][nt][r] + bv);
                } else {
                    ushortx* vt = (ushortx*)Vout;
                    const int cb = col - 2 * DIM;
                    const int hh = cb >> 6, dd = cb & 63;
                    const int bb = rbase >> 10, s0 = rbase & 1023;
                    ushort4 pk = { bf16lo(acc[mt][nt][0] + bv), bf16lo(acc[mt][nt][1] + bv),
                                   bf16lo(acc[mt][nt][2] + bv), bf16lo(acc[mt][nt][3] + bv) };
                    *(ushort4*)&vt[((size_t)((bb * 16 + hh) * 64 + dd) << 10) + s0] = pk;
                }
            }
        }
    }
}

// ---------------------------------------------------------------------------
// MFMA flash attention, bf16 inputs (qk[tok][2048], vT[(b*16+h)*64+d][SEQ]).
// Block = 4 waves, 64 queries of one (b,h). Output bf16 [tok][DIM].
// ---------------------------------------------------------------------------
__global__ __launch_bounds__(256)
void attn_full(const ushortx* __restrict__ qk, const ushortx* __restrict__ vt,
               ushortx* __restrict__ outb)
{
    __shared__ ushortx Qs[64][72];
    __shared__ ushortx Ks[64][72];
    __shared__ ushortx VT[64][72];        // VT[d][key]
    __shared__ ushortx Ps[4][16][72];

    const int blk = blockIdx.x;
    const int q0 = (blk & 15) * 64;
    const int h  = (blk >> 4) & 15;
    const int b  = blk >> 8;
    const int t  = threadIdx.x;
    const int w = t >> 6, lane = t & 63;
    const int quad = lane >> 4, l16 = lane & 15;

    #pragma unroll
    for (int i = 0; i < 2; ++i) {
        const int c = t + 256 * i, row = c >> 3, c8 = (c & 7) * 8;
        *(u16x8*)&Qs[row][c8] =
            *(const u16x8*)(qk + (size_t)(b * SEQ + q0 + row) * (2 * DIM) + h * HDIM + c8);
    }
    __syncthreads();

    bf16x8 aq[2];
    aq[0] = *(const bf16x8*)&Qs[w * 16 + l16][quad * 8];
    aq[1] = *(const bf16x8*)&Qs[w * 16 + l16][32 + quad * 8];

    float m_r[4] = {-1e30f, -1e30f, -1e30f, -1e30f};
    float l_r[4] = {0.f, 0.f, 0.f, 0.f};
    f32x4 Oa[4];
    #pragma unroll
    for (int nt = 0; nt < 4; ++nt) Oa[nt] = (f32x4){0.f, 0.f, 0.f, 0.f};

    for (int kt = 0; kt < SEQ / 64; ++kt) {
        __syncthreads();
        #pragma unroll
        for (int i = 0; i < 2; ++i) {
            const int c = t + 256 * i, row = c >> 3, c8 = (c & 7) * 8;
            *(u16x8*)&Ks[row][c8] = *(const u16x8*)(
                qk + (size_t)(b * SEQ + kt * 64 + row) * (2 * DIM) + DIM + h * HDIM + c8);
            *(u16x8*)&VT[row][c8] = *(const u16x8*)(
                vt + ((size_t)((b * 16 + h) * 64 + row) << 10) + kt * 64 + c8);
        }
        __syncthreads();

        f32x4 s[4];
        #pragma unroll
        for (int nt = 0; nt < 4; ++nt) {
            bf16x8 bk0 = *(const bf16x8*)&Ks[nt * 16 + l16][quad * 8];
            bf16x8 bk1 = *(const bf16x8*)&Ks[nt * 16 + l16][32 + quad * 8];
            s[nt] = __builtin_amdgcn_mfma_f32_16x16x32_bf16(aq[0], bk0,
                        (f32x4){0.f, 0.f, 0.f, 0.f}, 0, 0, 0);
            s[nt] = __builtin_amdgcn_mfma_f32_16x16x32_bf16(aq[1], bk1, s[nt], 0, 0, 0);
        }
        float tm[4], alpha[4];
        #pragma unroll
        for (int r = 0; r < 4; ++r) {
            float v = fmaxf(fmaxf(s[0][r], s[1][r]), fmaxf(s[2][r], s[3][r])) * 0.125f;
            #pragma unroll
            for (int off = 1; off < 16; off <<= 1) v = fmaxf(v, __shfl_xor(v, off));
            tm[r] = v;
        }
        #pragma unroll
        for (int r = 0; r < 4; ++r) {
            const float mn = fmaxf(m_r[r], tm[r]);
            alpha[r] = __expf(m_r[r] - mn);
            m_r[r] = mn;
        }
        float rs[4] = {0.f, 0.f, 0.f, 0.f};
        #pragma unroll
        for (int nt = 0; nt < 4; ++nt) {
            #pragma unroll
            for (int r = 0; r < 4; ++r) {
                const float p = __expf(s[nt][r] * 0.125f - m_r[r]);
                rs[r] += p;
                Ps[w][quad * 4 + r][nt * 16 + l16] = bf16lo(p);
            }
        }
        #pragma unroll
        for (int r = 0; r < 4; ++r) {
            float v = rs[r];
            #pragma unroll
            for (int off = 1; off < 16; off <<= 1) v += __shfl_xor(v, off);
            l_r[r] = l_r[r] * alpha[r] + v;
            #pragma unroll
            for (int nt = 0; nt < 4; ++nt) Oa[nt][r] *= alpha[r];
        }
        bf16x8 pa0 = *(const bf16x8*)&Ps[w][l16][quad * 8];
        bf16x8 pa1 = *(const bf16x8*)&Ps[w][l16][32 + quad * 8];
        #pragma unroll
        for (int nt = 0; nt < 4; ++nt) {
            bf16x8 bv0 = *(const bf16x8*)&VT[nt * 16 + l16][quad * 8];
            bf16x8 bv1 = *(const bf16x8*)&VT[nt * 16 + l16][32 + quad * 8];
            Oa[nt] = __builtin_amdgcn_mfma_f32_16x16x32_bf16(pa0, bv0, Oa[nt], 0, 0, 0);
            Oa[nt] = __builtin_amdgcn_mfma_f32_16x16x32_bf16(pa1, bv1, Oa[nt], 0, 0, 0);
        }
    }
    float inv[4];
    #pragma unroll
    for (int r = 0; r < 4; ++r) inv[r] = 1.f / l_r[r];
    #pragma unroll
    for (int r = 0; r < 4; ++r) {
        const size_t row = (size_t)(b * SEQ + q0 + w * 16 + quad * 4 + r);
        #pragma unroll
        for (int nt = 0; nt < 4; ++nt)
            outb[row * DIM + h * HDIM + nt * 16 + l16] = bf16lo(Oa[nt][r] * inv[r]);
    }
}

// ---------------------------------------------------------------------------
// Banded attention (|s-t| <= 2), one wave per (b,h,s), bf16 in/out.
// ---------------------------------------------------------------------------
__global__ __launch_bounds__(64)
void attn_band(const ushortx* __restrict__ qk, const ushortx* __restrict__ vt,
               ushortx* __restrict__ outb)
{
    const int gid = blockIdx.x;
    const int s = gid & (SEQ - 1);
    const int h = (gid >> 10) & (NH - 1);
    const int b = gid >> 14;
    const int lane = threadIdx.x;
    const float qd = bf2f(qk[(size_t)(b * SEQ + s) * (2 * DIM) + h * HDIM + lane]);
    const int t0 = max(s - 2, 0);
    const int t1 = min(s + 2, SEQ - 1);
    const int cnt = t1 - t0 + 1;
    float p[5];
    float m = -1e30f;
    for (int i = 0; i < cnt; ++i) {
        const int tt = t0 + i;
        float prod = qd * bf2f(qk[(size_t)(b * SEQ + tt) * (2 * DIM) + DIM + h * HDIM + lane]);
        #pragma unroll
        for (int off = 32; off > 0; off >>= 1) prod += __shfl_xor(prod, off);
        p[i] = prod * 0.125f;
        m = fmaxf(m, p[i]);
    }
    float sum = 0.f;
    for (int i = 0; i < cnt; ++i) { p[i] = __expf(p[i] - m); sum += p[i]; }
    float acc = 0.f;
    const ushortx* vrow = vt + ((size_t)((b * 16 + h) * 64 + lane) << 10);
    for (int i = 0; i < cnt; ++i) acc += p[i] * bf2f(vrow[t0 + i]);
    outb[(size_t)(b * SEQ + s) * DIM + h * HDIM + lane] = bf16lo(acc / sum);
}

// ---------------------------------------------------------------------------
// out = LN( x (+y) ) * g + b — fp32 out and/or bf16 out.
// ---------------------------------------------------------------------------
__global__ __launch_bounds__(256)
void add_ln(const float* __restrict__ x, const float* __restrict__ y,
            const float* __restrict__ g, const float* __restrict__ be,
            float* __restrict__ outf, ushortx* __restrict__ outb, int hasY)
{
    __shared__ float row[DIM];
    __shared__ float red[256];
    const int n = blockIdx.x;
    const int tid = threadIdx.x;
    float lsum = 0.f;
    for (int i = tid; i < DIM; i += 256) {
        float v = x[(size_t)n * DIM + i];
        if (hasY) v += y[(size_t)n * DIM + i];
        row[i] = v;
        lsum += v;
    }
    red[tid] = lsum;
    __syncthreads();
    for (int ofs = 128; ofs > 0; ofs >>= 1) {
        if (tid < ofs) red[tid] += red[tid + ofs];
        __syncthreads();
    }
    const float mu = red[0] * (1.f / DIM);
    __syncthreads();
    float lvar = 0.f;
    for (int i = tid; i < DIM; i += 256) {
        const float d = row[i] - mu;
        lvar += d * d;
    }
    red[tid] = lvar;
    __syncthreads();
    for (int ofs = 128; ofs > 0; ofs >>= 1) {
        if (tid < ofs) red[tid] += red[tid + ofs];
        __syncthreads();
    }
    const float rstd = rsqrtf(red[0] * (1.f / DIM) + LN_EPS);
    __syncthreads();
    for (int i = tid; i < DIM; i += 256) {
        const float o = (row[i] - mu) * rstd * g[i] + be[i];
        if (outf) outf[(size_t)n * DIM + i] = o;
        if (outb) outb[(size_t)n * DIM + i] = bf16lo(o);
    }
}

__global__ __launch_bounds__(256)
void add_vec(const float* __restrict__ a, const float* __restrict__ b,
             float* __restrict__ outf, ushortx* __restrict__ outb)
{
    const size_t i = (size_t)blockIdx.x * 256 + threadIdx.x;
    const float v = a[i] + b[i];
    outf[i] = v;
    outb[i] = bf16lo(v);
}

// ---------------------------------------------------------------------------
extern "C" void kernel_launch(void* const* d_in, const int* in_sizes, int n_in,
                              void* d_out, int out_size, void* d_ws, size_t ws_size,
                              hipStream_t stream)
{
    const float* x0     = (const float*)d_in[0];
    const float* w_in1  = (const float*)d_in[1];
    const float* b_in1  = (const float*)d_in[2];
    const float* w_out1 = (const float*)d_in[3];
    const float* b_out1 = (const float*)d_in[4];
    const float* ln1_g  = (const float*)d_in[5];
    const float* ln1_b  = (const float*)d_in[6];
    const float* w_in2  = (const float*)d_in[7];
    const float* b_in2  = (const float*)d_in[8];
    const float* w_out2 = (const float*)d_in[9];
    const float* b_out2 = (const float*)d_in[10];
    const float* fw1    = (const float*)d_in[11];
    const float* fb1    = (const float*)d_in[12];
    const float* fw2    = (const float*)d_in[13];
    const float* fb2    = (const float*)d_in[14];
    const float* lnf_g  = (const float*)d_in[15];
    const float* lnf_b  = (const float*)d_in[16];
    // NOTE: inputs in setup_inputs() order (19 entries incl. zeros biases):
    // re-index properly below (ffn at 13..16, lnf at 17,18)
    fw1   = (const float*)d_in[13];
    fb1   = (const float*)d_in[14];
    fw2   = (const float*)d_in[15];
    fb2   = (const float*)d_in[16];
    lnf_g = (const float*)d_in[17];
    lnf_b = (const float*)d_in[18];
    w_in2  = (const float*)d_in[7];
    b_in2  = (const float*)d_in[8];
    w_out2 = (const float*)d_in[9];
    b_out2 = (const float*)d_in[10];
    const float* ln2_g = (const float*)d_in[11];
    const float* ln2_b = (const float*)d_in[12];
    float* out = (float*)d_out;

    char* W = (char*)d_ws;
    float*   xb    = (float*)(W);                          // 8 MB residual
    float*   t2    = (float*)(W + ((size_t)8  << 20));     // 8 MB proj/ffn2 out
    float*   attf  = (float*)(W + ((size_t)16 << 20));     // 8 MB attended fp32
    ushortx* actbf = (ushortx*)(W + ((size_t)24 << 20));   // 4 MB shared bf16 act
    ushortx* qkb   = (ushortx*)(W + ((size_t)28 << 20));   // 8 MB qk bf16
    ushortx* vtb   = (ushortx*)(W + ((size_t)36 << 20));   // 4 MB vT bf16
    ushortx* hbf   = (ushortx*)(W + ((size_t)28 << 20));   // 16 MB (alias qkb+vtb)
    ushortx* wbf   = (ushortx*)(W + ((size_t)44 << 20));   // 32 MB weights bf16

    const size_t OFF_WI1 = 0,        OFF_WO1 = 3145728;
    const size_t OFF_WI2 = 4194304,  OFF_WO2 = 7340032;
    const size_t OFF_W1  = 8388608,  OFF_W2  = 12582912;

    init_x<<<dim3(NTOK * DIM / 256), dim3(256), 0, stream>>>(x0, xb, actbf);

    const dim3 blk(256);
    for (int l = 0; l < NLAYER; ++l) {
        const float* bi1 = b_in1  + (size_t)l * 3 * DIM;
        const float* bo1 = b_out1 + (size_t)l * DIM;
        const float* g1  = ln1_g  + (size_t)l * DIM;
        const float* be1 = ln1_b  + (size_t)l * DIM;
        const float* bi2 = b_in2  + (size_t)l * 3 * DIM;
        const float* bo2 = b_out2 + (size_t)l * DIM;
        const float* g2  = ln2_g  + (size_t)l * DIM;
        const float* be2 = ln2_b  + (size_t)l * DIM;
        const float* b1l = fb1    + (size_t)l * MLP;
        const float* b2l = fb2    + (size_t)l * DIM;

        cvt_w<<<dim3(2048), blk, 0, stream>>>(
            w_in1 + (size_t)l * 3 * DIM * DIM, w_out1 + (size_t)l * DIM * DIM,
            w_in2 + (size_t)l * 3 * DIM * DIM, w_out2 + (size_t)l * DIM * DIM,
            fw1 + (size_t)l * MLP * DIM, fw2 + (size_t)l * DIM * MLP, wbf);

        // 1. qkv1 (q,k -> qkb; v -> vtb transposed)
        gemm_bf<128, 128, 2><<<dim3(3 * DIM / 128, NTOK / 128), blk, 0, stream>>>(
            actbf, wbf + OFF_WI1, bi1, qkb, vtb, DIM, 0);
        // 2. full attention
        attn_full<<<dim3(BATCH * NH * (SEQ / 64)), blk, 0, stream>>>(qkb, vtb, actbf);
        // 3. proj1
        gemm_bf<64, 64, 0><<<dim3(DIM / 64, NTOK / 64), blk, 0, stream>>>(
            actbf, wbf + OFF_WO1, bo1, t2, nullptr, DIM, DIM);
        // 4. x = LN(x + proj)  (fp32 + bf16)
        add_ln<<<dim3(NTOK), blk, 0, stream>>>(xb, t2, g1, be1, xb, actbf, 1);
        // 5. qkv2
        gemm_bf<128, 128, 2><<<dim3(3 * DIM / 128, NTOK / 128), blk, 0, stream>>>(
            actbf, wbf + OFF_WI2, bi2, qkb, vtb, DIM, 0);
        // 6. banded attention
        attn_band<<<dim3(BATCH * NH * SEQ), dim3(64), 0, stream>>>(qkb, vtb, actbf);
        // 7. proj2
        gemm_bf<64, 64, 0><<<dim3(DIM / 64, NTOK / 64), blk, 0, stream>>>(
            actbf, wbf + OFF_WO2, bo2, t2, nullptr, DIM, DIM);
        // 8. attended = LN(x + proj2)
        add_ln<<<dim3(NTOK), blk, 0, stream>>>(xb, t2, g2, be2, attf, actbf, 1);
        // 9. h = gelu(att @ fw1^T + fb1) -> bf16
        gemm_bf<128, 128, 1><<<dim3(MLP / 128, NTOK / 128), blk, 0, stream>>>(
            actbf, wbf + OFF_W1, b1l, hbf, nullptr, DIM, MLP);
        // 10. t2 = h @ fw2^T + fb2
        gemm_bf<64, 64, 0><<<dim3(DIM / 64, NTOK / 64), blk, 0, stream>>>(
            hbf, wbf + OFF_W2, b2l, t2, nullptr, MLP, DIM);
        // 11. x = attended + t2 (fp32 + bf16)
        add_vec<<<dim3(NTOK * DIM / 256), blk, 0, stream>>>(attf, t2, xb, actbf);
    }
    add_ln<<<dim3(NTOK), blk, 0, stream>>>(xb, nullptr, lnf_g, lnf_b, out, nullptr, 0);
}